// Round 8
// baseline (2109.861 us; speedup 1.0000x reference)
//
#include <hip/hip_runtime.h>
#include <cstddef>

#define LOG2E 1.4426950408889634f
#define LN2   0.6931471805599453f

typedef float    f32x2 __attribute__((ext_vector_type(2)));
typedef float    f32x4 __attribute__((ext_vector_type(4)));
typedef _Float16 half8 __attribute__((ext_vector_type(8)));

constexpr int K_    = 256;
constexpr int T_    = 2048;
constexpr int DMAX_ = 64;
constexpr int B_    = 16;

__device__ __forceinline__ float fexp2(float x) { return __builtin_amdgcn_exp2f(x); }
__device__ __forceinline__ float flog2(float x) { return __builtin_amdgcn_logf(x); }
__device__ __forceinline__ float frcp (float x) { return __builtin_amdgcn_rcpf(x); }

// cross-half (lane ^ 32) exchange via v_permlane32_swap_b32 (VALU).
// fmax/sum over {r.x, r.y} is correct under either HW swap convention; the
// "other half's value" is whichever element differs from own.
__device__ __forceinline__ f32x2 xchg32(float x) {
    float a = x, b;
    asm("v_mov_b32 %1, %2\n\t"
        "s_nop 1\n\t"
        "v_permlane32_swap_b32 %0, %1"
        : "+v"(a), "=&v"(b)
        : "v"(x));
    return (f32x2){a, b};
}

// max-reduce across a 16-lane row via DPP row_ror (VALU, no LDS pipe).
template<int CTRL>
__device__ __forceinline__ float dpp_maxf(float x) {
    int m = __builtin_amdgcn_update_dpp(0, __builtin_bit_cast(int, x), CTRL, 0xF, 0xF, true);
    return fmaxf(x, __builtin_bit_cast(float, m));
}

// BATCH-PACKED R4 structure: 8 blocks, each block advances TWO sequences
// (bA = 2*blk, bB = 2*blk+1) per step with ONE matvec.
//   MFMA A-matrix rows: row%4==0 -> pA, row%4==1 -> pB, rows 2,3%4 -> 0.
//   C/D row = 4*(lane>>4)+reg  =>  d.x = a_in_A[col], d.y = a_in_B[col] for
//   EVERY lane group -- no extra cross-lane traffic vs single-batch R4.
// Per block-step (2 batch-steps): same 72 af-LDS ops, 16 MFMAs/wave, 1
// barrier as R4's single-batch step; only dot/shift/scalars double (~2x
// VALU), which sits under the LDS burst. Lane map as R4: j=(w<<5)|(lane&31),
// q=lane>>5 owns ages 32q+1..32q+32 as pairs {32q+1+i, 32q+17+i}, for BOTH
// batches (vA/vB). pD and Bf shared between batches.
__global__ __launch_bounds__(512)
__attribute__((amdgpu_waves_per_eu(2, 2)))
void hsmm_fwd_kernel(const float* __restrict__ logB,   // [B,T,K]
                     const float* __restrict__ pi,     // [K]
                     const float* __restrict__ A,      // [K,K]
                     const float* __restrict__ D,      // [K,DMAX]
                     float* __restrict__ out)          // [16] loglik ++ [B,T,K] alphas
{
    const int blk  = blockIdx.x;               // 0..7
    const int bA   = blk << 1, bB = bA | 1;
    const int tid  = threadIdx.x;
    const int w    = tid >> 6;
    const int lane = tid & 63;
    const int j    = (w << 5) | (lane & 31);   // column 0..255
    const int q    = lane >> 5;                // age half

    alignas(16) __shared__ _Float16 lds_p[2][512];  // [parity][pA[256] ++ pB[256]]
    alignas(16) __shared__ _Float16 lds_z[256];     // zero page for dead A-rows
    alignas(16) __shared__ float    lds_red[16];    // [w*2+{0:A,1:B}] anchor feed

    // ---- init: B-fragments (P = exp(A_logits), f16, MFMA B-layout) ----
    half8 Bf0[8], Bf1[8];
    {
        const int krow = (lane >> 4) * 8;
        const int n0   = (w << 5) + (lane & 15);
        #pragma unroll
        for (int kc = 0; kc < 8; ++kc) {
            #pragma unroll
            for (int jj = 0; jj < 8; ++jj) {
                const int k = kc * 32 + krow + jj;
                Bf0[kc][jj] = (_Float16)fexp2(A[(size_t)k * K_ + n0     ] * LOG2E);
                Bf1[kc][jj] = (_Float16)fexp2(A[(size_t)k * K_ + n0 + 16] * LOG2E);
            }
        }
    }
    // pD pairs (shared by both batches): pDf[i] = {pD(32q+1+i), pD(32q+17+i)}
    f32x2 pDf[16];
    {
        const float* Dj = D + (size_t)j * DMAX_ + 32 * q;
        #pragma unroll
        for (int i = 0; i < 16; ++i)
            pDf[i] = (f32x2){ fexp2(Dj[i] * LOG2E), fexp2(Dj[16 + i] * LOG2E) };
    }

    // duration-age state, one set per batch
    f32x2 vA[16], vB[16];
    #pragma unroll
    for (int i = 0; i < 16; ++i) { vA[i] = (f32x2){0.f,0.f}; vB[i] = (f32x2){0.f,0.f}; }
    if (q == 0) { vA[0].x = 1.0f; vB[0].x = 1.0f; }
    float mcA = pi[j] * LOG2E, mcB = mcA;      // column anchors (base-2)
    float cbA = 0.0f, cbB = 0.0f;              // cum emissions (base-2)
    float maA = 0.0f, maB = 0.0f;              // block anchors (lag 2-3)

    // af read pointers: A-row m = lane&15; m%4==0 -> pA, ==1 -> pB, else zero
    const int sel = lane & 3;
    const int fo  = (lane >> 4) * 8;
    const _Float16* a0 = (sel == 0) ? &lds_p[0][fo]
                       : (sel == 1) ? &lds_p[0][256 + fo] : &lds_z[fo];
    const _Float16* a1 = (sel == 0) ? &lds_p[1][fo]
                       : (sel == 1) ? &lds_p[1][256 + fo] : &lds_z[fo];
    _Float16* wp0 = &lds_p[0][(q << 8) + j];   // q0 writes pA[j], q1 pB[j]
    _Float16* wp1 = &lds_p[1][(q << 8) + j];

    if (tid < 16)  lds_red[tid] = 0.0f;
    if (tid < 256) lds_z[tid]   = (_Float16)0.0f;
    __syncthreads();

    const float* lbA = logB + (size_t)bA * T_ * K_ + j;
    const float* lbB = logB + (size_t)bB * T_ * K_ + j;
    float*       aoP = out + 16 + (size_t)(q ? bB : bA) * T_ * K_ + j;

    // depth-3 prefetch rings, one per batch
    float fA0 = lbA[0], fA1 = lbA[K_], fA2 = lbA[2 * K_];
    float fB0 = lbB[0], fB1 = lbB[K_], fB2 = lbB[2 * K_];
    int   ldoff = 3 * K_;
    int   aoff  = 0;

    // static even/odd body (EVEN: anchor-feed write; ODD: anchor update)
    auto body = [&](int s, bool even, bool upd) __attribute__((always_inline)) {
        cbA = fmaf(fA0, LOG2E, cbA);
        cbB = fmaf(fB0, LOG2E, cbB);

        const float exA = fexp2(0.5f * (cbA + mcA - maA));
        const float eaA = fminf(exA, 1.8e19f), gaA = fminf(frcp(exA), 1.8e19f);
        const float mmA = maA - cbA;
        const float exB = fexp2(0.5f * (cbB + mcB - maB));
        const float eaB = fminf(exB, 1.8e19f), gaB = fminf(frcp(exB), 1.8e19f);
        const float mmB = maB - cbB;

        // ---- duration dots: 2 x 16 pk_fma + trees + 1 xchg32 each ----
        f32x2 t0={0.f,0.f}, t1={0.f,0.f}, t2={0.f,0.f}, t3={0.f,0.f};
        f32x2 u0={0.f,0.f}, u1={0.f,0.f}, u2={0.f,0.f}, u3={0.f,0.f};
        #pragma unroll
        for (int i = 0; i < 16; i += 4) {
            t0 = __builtin_elementwise_fma(vA[i + 0], pDf[i + 0], t0);
            t1 = __builtin_elementwise_fma(vA[i + 1], pDf[i + 1], t1);
            t2 = __builtin_elementwise_fma(vA[i + 2], pDf[i + 2], t2);
            t3 = __builtin_elementwise_fma(vA[i + 3], pDf[i + 3], t3);
            u0 = __builtin_elementwise_fma(vB[i + 0], pDf[i + 0], u0);
            u1 = __builtin_elementwise_fma(vB[i + 1], pDf[i + 1], u1);
            u2 = __builtin_elementwise_fma(vB[i + 2], pDf[i + 2], u2);
            u3 = __builtin_elementwise_fma(vB[i + 3], pDf[i + 3], u3);
        }
        f32x2 spA = (t0 + t1) + (t2 + t3);
        f32x2 spB = (u0 + u1) + (u2 + u3);
        f32x2 prA = xchg32(spA.x + spA.y);
        f32x2 prB = xchg32(spB.x + spB.y);
        const float SA = prA.x + prA.y;
        const float SB = prB.x + prB.y;

        const float pAv = fminf(SA * eaA * eaA, 60000.0f);  // f16 clamp
        const float pBv = fminf(SB * eaB * eaB, 60000.0f);
        (s ? wp1 : wp0)[0] = (_Float16)(q ? pBv : pAv);

        // ---- the ONE barrier: pinned so no LDS op crosses it ----
        asm volatile("s_waitcnt lgkmcnt(0)" ::: "memory");
        __builtin_amdgcn_sched_barrier(0);
        __builtin_amdgcn_s_barrier();
        __builtin_amdgcn_sched_barrier(0);

        // globals: prefetch t+3 (in flight across barriers) + alpha store
        fA0 = fA1; fA1 = fA2; fA2 = lbA[ldoff];
        fB0 = fB1; fB1 = fB2; fB2 = lbB[ldoff];
        ldoff += (ldoff < (T_ - 1) * K_) ? K_ : 0;
        aoP[aoff] = q ? (cbB + mcB + flog2(SB)) * LN2
                      : (cbA + mcA + flog2(SA)) * LN2;
        aoff += K_;

        f32x4 r0, r1, r2, r3;
        if (!even) {    // hoisted anchor read (broadcast, overlaps MFMA)
            r0 = ((const f32x4*)lds_red)[0];
            r1 = ((const f32x4*)lds_red)[1];
            r2 = ((const f32x4*)lds_red)[2];
            r3 = ((const f32x4*)lds_red)[3];
        }

        // ---- MFMA matvec: 8 shared af reads, 16 MFMAs, both batches ----
        const _Float16* pb = s ? a1 : a0;
        const f32x4 z = {0.f,0.f,0.f,0.f};
        f32x4 d0a = z, d0b = z, d1a = z, d1b = z;
        #pragma unroll
        for (int kc = 0; kc < 4; ++kc) {
            half8 af = *(const half8*)(pb + kc * 32);
            d0a = __builtin_amdgcn_mfma_f32_16x16x32_f16(af, Bf0[kc], d0a, 0, 0, 0);
            d1a = __builtin_amdgcn_mfma_f32_16x16x32_f16(af, Bf1[kc], d1a, 0, 0, 0);
        }
        #pragma unroll
        for (int kc = 4; kc < 8; ++kc) {
            half8 af = *(const half8*)(pb + kc * 32);
            d0b = __builtin_amdgcn_mfma_f32_16x16x32_f16(af, Bf0[kc], d0b, 0, 0, 0);
            d1b = __builtin_amdgcn_mfma_f32_16x16x32_f16(af, Bf1[kc], d1b, 0, 0, 0);
        }
        const float s0x = d0a.x + d0b.x, s1x = d1a.x + d1b.x;  // batch A
        const float s0y = d0a.y + d0b.y, s1y = d1a.y + d1b.y;  // batch B
        const float smA = (lane & 16) ? s1x : s0x;             // own column
        const float smB = (lane & 16) ? s1y : s0y;

        float mnA = 0.0f, mnB = 0.0f;
        if (even) {
            float mxA = fmaxf(s0x, s1x), mxB = fmaxf(s0y, s1y);
            mxA = dpp_maxf<0x121>(mxA); mxB = dpp_maxf<0x121>(mxB);
            mxA = dpp_maxf<0x122>(mxA); mxB = dpp_maxf<0x122>(mxB);
            mxA = dpp_maxf<0x124>(mxA); mxB = dpp_maxf<0x124>(mxB);
            mxA = dpp_maxf<0x128>(mxA); mxB = dpp_maxf<0x128>(mxB);
            if (lane == 0)
                *(f32x2*)&lds_red[w * 2] = (f32x2){
                    maA + flog2(fmaxf(mxA, 1e-30f)),
                    maB + flog2(fmaxf(mxB, 1e-30f)) };
        } else {
            mnA = fmaxf(fmaxf(fmaxf(r0.x, r0.z), fmaxf(r1.x, r1.z)),
                        fmaxf(fmaxf(r2.x, r2.z), fmaxf(r3.x, r3.z)));
            mnB = fmaxf(fmaxf(fmaxf(r0.y, r0.w), fmaxf(r1.y, r1.w)),
                        fmaxf(fmaxf(r2.y, r2.w), fmaxf(r3.y, r3.w)));
        }

        // ---- tails + PAIR shift/rescale, per batch ----
        const float n0A = smA * gaA * gaA;
        const float rsA = frcp(fmaxf(n0A, 1.0f));
        const float nvA = fminf(n0A, 1.0f);
        mcA = fmaxf(mcA, mmA + flog2(smA));
        const float n0B = smB * gaB * gaB;
        const float rsB = frcp(fmaxf(n0B, 1.0f));
        const float nvB = fminf(n0B, 1.0f);
        mcB = fmaxf(mcB, mmB + flog2(smB));

        f32x2 hA = xchg32(vA[15].y);
        f32x2 hB = xchg32(vB[15].y);
        const float oA = (hA.x == vA[15].y) ? hA.y : hA.x;
        const float oB = (hB.x == vB[15].y) ? hB.y : hB.x;
        const float pxA = vA[15].x, pxB = vB[15].x;
        const f32x2 rpA = { rsA, rsA }, rpB = { rsB, rsB };
        #pragma unroll
        for (int k = 15; k >= 1; --k) {
            vA[k] = vA[k - 1] * rpA;
            vB[k] = vB[k - 1] * rpB;
        }
        vA[0].y = pxA * rsA;  vA[0].x = (q == 0) ? nvA : oA * rsA;
        vB[0].y = pxB * rsB;  vB[0].x = (q == 0) ? nvB : oB * rsB;

        if (!even && upd) { maA = mnA; maB = mnB; }  // keep final anchor for loglik
    };

    for (int t = 0; t < T_; t += 2) {
        body(0, true,  true);
        body(1, false, t + 2 < T_);
    }

    // ---- loglik: lds_p[1] holds f16 exp2(alpha_{T-1} - m_anchor), per batch ----
    if (tid < 128) {
        const int g64 = tid >> 6;                       // 0: batch A, 1: batch B
        const _Float16* lp = lds_p[1] + (g64 << 8);
        const int l6 = tid & 63;
        float sf = (float)lp[l6] + (float)lp[l6 + 64]
                 + (float)lp[l6 + 128] + (float)lp[l6 + 192];
        #pragma unroll
        for (int off = 1; off < 64; off <<= 1)
            sf += __shfl_xor(sf, off, 64);
        if (l6 == 0)
            out[g64 ? bB : bA] = ((g64 ? maB : maA) + flog2(sf)) * LN2;
    }
}

extern "C" void kernel_launch(void* const* d_in, const int* in_sizes, int n_in,
                              void* d_out, int out_size, void* d_ws, size_t ws_size,
                              hipStream_t stream) {
    const float* logB = (const float*)d_in[0];   // [16,2048,256]
    const float* pi   = (const float*)d_in[1];   // [256]
    const float* A    = (const float*)d_in[2];   // [256,256]
    const float* D    = (const float*)d_in[3];   // [256,64]
    float* out = (float*)d_out;
    (void)in_sizes; (void)n_in; (void)d_ws; (void)ws_size; (void)out_size;

    hipLaunchKernelGGL(hsmm_fwd_kernel, dim3(B_ / 2), dim3(512), 0, stream,
                       logB, pi, A, D, out);
}

// Round 10
// 1469.396 us; speedup vs baseline: 1.4359x; 1.4359x over previous
//
#include <hip/hip_runtime.h>
#include <cstddef>

#define LOG2E 1.4426950408889634f
#define LN2   0.6931471805599453f

typedef float    f32x2 __attribute__((ext_vector_type(2)));
typedef float    f32x4 __attribute__((ext_vector_type(4)));
typedef _Float16 half8 __attribute__((ext_vector_type(8)));

constexpr int K_    = 256;
constexpr int T_    = 2048;
constexpr int DMAX_ = 64;
constexpr int B_    = 16;

__device__ __forceinline__ float fexp2(float x) { return __builtin_amdgcn_exp2f(x); }
__device__ __forceinline__ float flog2(float x) { return __builtin_amdgcn_logf(x); }
__device__ __forceinline__ float frcp (float x) { return __builtin_amdgcn_rcpf(x); }

// ---- forced VOP3P packed-f32 ops (hipcc often scalarizes f32x2 math) ----
__device__ __forceinline__ f32x2 pk_fma(f32x2 a, f32x2 b, f32x2 c) {
    f32x2 d;
    asm("v_pk_fma_f32 %0, %1, %2, %3" : "=v"(d) : "v"(a), "v"(b), "v"(c));
    return d;
}
__device__ __forceinline__ f32x2 pk_mul(f32x2 a, f32x2 b) {
    f32x2 d;
    asm("v_pk_mul_f32 %0, %1, %2" : "=v"(d) : "v"(a), "v"(b));
    return d;
}
__device__ __forceinline__ f32x2 pk_add(f32x2 a, f32x2 b) {
    f32x2 d;
    asm("v_pk_add_f32 %0, %1, %2" : "=v"(d) : "v"(a), "v"(b));
    return d;
}

// cross-half (lane ^ 32) exchange via v_permlane32_swap_b32 (VALU).
// %1 early-clobber guarantees distinct regs; r.x+r.y = cross-half sum under
// either HW swap convention; "other half's value" = element differing from own.
__device__ __forceinline__ f32x2 xchg32(float x) {
    float a = x, b;
    asm("v_mov_b32 %1, %2\n\t"
        "s_nop 1\n\t"
        "v_permlane32_swap_b32 %0, %1"
        : "+v"(a), "=&v"(b)
        : "v"(x));
    return (f32x2){a, b};
}

// max-reduce across a 16-lane row via DPP row_ror (VALU, no LDS pipe).
template<int CTRL>
__device__ __forceinline__ float dpp_maxf(float x) {
    int m = __builtin_amdgcn_update_dpp(0, __builtin_bit_cast(int, x), CTRL, 0xF, 0xF, true);
    return fmaxf(x, __builtin_bit_cast(float, m));
}

// R4 structure (proven 1385 us) + forced v_pk_* VOP3P on dot/shift/tree.
// 512 threads = 8 waves, 2 waves/SIMD. Wave w owns columns 32w..32w+31.
// Lane map: j = (w<<5)|(lane&31); q = lane>>5 owns ages 32q+1..32q+32 as
// pairs v[i] = {32q+1+i, 32q+17+i} (pair-shift layout).
// Anchor machinery at half rate (even: DPP max + lds_red write; odd: read +
// reduce). One pinned barrier per step; depth-3 global prefetch ring.
__global__ __launch_bounds__(512)
__attribute__((amdgpu_waves_per_eu(2, 2)))
void hsmm_fwd_kernel(const float* __restrict__ logB,   // [B,T,K]
                     const float* __restrict__ pi,     // [K]
                     const float* __restrict__ A,      // [K,K]
                     const float* __restrict__ D,      // [K,DMAX]
                     float* __restrict__ out)          // [16] loglik ++ [B,T,K] alphas
{
    const int b    = blockIdx.x;
    const int tid  = threadIdx.x;
    const int w    = tid >> 6;
    const int lane = tid & 63;
    const int j    = (w << 5) | (lane & 31);   // column 0..255
    const int q    = lane >> 5;                // age half

    alignas(16) __shared__ _Float16 lds_ph[2][K_];    // p f16, ping-pong by t&1
    alignas(16) __shared__ float    lds_red[8];       // per-wave max a_in

    // ---- init: B-fragments (P = exp(A_logits), f16, MFMA B-layout) ----
    half8 Bf0[8], Bf1[8];
    {
        const int krow = (lane >> 4) * 8;
        const int n0   = (w << 5) + (lane & 15);
        #pragma unroll
        for (int kc = 0; kc < 8; ++kc) {
            #pragma unroll
            for (int jj = 0; jj < 8; ++jj) {
                const int k = kc * 32 + krow + jj;
                Bf0[kc][jj] = (_Float16)fexp2(A[(size_t)k * K_ + n0     ] * LOG2E);
                Bf1[kc][jj] = (_Float16)fexp2(A[(size_t)k * K_ + n0 + 16] * LOG2E);
            }
        }
    }
    // pD in PAIR layout: pDf[i] = {pD(age 32q+1+i), pD(age 32q+17+i)}
    f32x2 pDf[16];
    {
        const float* Dj = D + (size_t)j * DMAX_ + 32 * q;
        #pragma unroll
        for (int i = 0; i < 16; ++i)
            pDf[i] = (f32x2){ fexp2(Dj[i] * LOG2E), fexp2(Dj[16 + i] * LOG2E) };
    }

    // v[i] = values at ages {32q+1+i, 32q+17+i}
    f32x2 v[16];
    #pragma unroll
    for (int i = 0; i < 16; ++i) v[i] = (f32x2){0.0f, 0.0f};
    if (q == 0) v[0].x = 1.0f;          // age-1 holds pi mass (anchor = pi)
    float mcol     = pi[j] * LOG2E;     // column anchor (base-2)
    float cumb     = 0.0f;
    float m_anchor = 0.0f;              // block anchor (lag 2-3)

    if (tid < 8) lds_red[tid] = 0.0f;
    __syncthreads();

    const float* lb = logB + (size_t)b * T_ * K_ + j;
    float*       ao = out + 16 + (size_t)b * T_ * K_ + j;

    // depth-3 prefetch ring for the per-step emission
    float bld0 = lb[0];
    float bld1 = lb[K_];
    float bld2 = lb[2 * K_];
    int   ldoff = 3 * K_;
    int   aoff  = 0;

    // static even/odd step body (EVEN: anchor-feed write; ODD: anchor update)
    auto body = [&](int t, int s, bool even) __attribute__((always_inline)) {
        cumb = fmaf(bld0, LOG2E, cumb);

        const float ex   = fexp2(0.5f * (cumb + mcol - m_anchor));
        const float ea   = fminf(ex, 1.8e19f);
        const float ga   = fminf(frcp(ex), 1.8e19f);   // exp2(-argh) via rcp
        const float mac  = m_anchor - cumb;

        // ---- duration dot: 16 v_pk_fma_f32 + pk tree + 1 permlane ----
        f32x2 s0 = {0.f,0.f}, s1 = {0.f,0.f}, s2 = {0.f,0.f}, s3 = {0.f,0.f};
        #pragma unroll
        for (int k = 0; k < 16; k += 4) {
            s0 = pk_fma(v[k + 0], pDf[k + 0], s0);
            s1 = pk_fma(v[k + 1], pDf[k + 1], s1);
            s2 = pk_fma(v[k + 2], pDf[k + 2], s2);
            s3 = pk_fma(v[k + 3], pDf[k + 3], s3);
        }
        f32x2 sp = pk_add(pk_add(s0, s1), pk_add(s2, s3));
        float Sl = sp.x + sp.y;
        f32x2 pr = xchg32(Sl);
        float S  = pr.x + pr.y;                 // full sum, direction-agnostic

        float p = fminf(S * ea * ea, 60000.0f); // f16-overflow clamp
        if (q == 0) lds_ph[s][j] = (_Float16)p;

        // ---- the ONE barrier: pinned so no LDS op crosses it ----
        asm volatile("s_waitcnt lgkmcnt(0)" ::: "memory");
        __builtin_amdgcn_sched_barrier(0);
        __builtin_amdgcn_s_barrier();
        __builtin_amdgcn_sched_barrier(0);

        // globals: prefetch t+3 (in flight across barriers) + alpha store
        bld0 = bld1; bld1 = bld2;
        bld2 = lb[ldoff];
        ldoff += (ldoff < (T_ - 1) * K_) ? K_ : 0;
        if (q == 0) ao[aoff] = (cumb + mcol + flog2(S)) * LN2;
        aoff += K_;

        f32x4 r0, r1;
        if (!even) {    // hoisted anchor read (latency overlaps MFMA)
            r0 = ((const f32x4*)lds_red)[0];
            r1 = ((const f32x4*)lds_red)[1];
        }

        // ---- MFMA matvec, 4 independent 4-deep chains ----
        const _Float16* pb = lds_ph[s];
        const int fo = (lane >> 4) * 8;
        const f32x4 z = {0.f,0.f,0.f,0.f};
        f32x4 d0a = z, d0b = z, d1a = z, d1b = z;
        #pragma unroll
        for (int kc = 0; kc < 4; ++kc) {
            half8 af = *(const half8*)(pb + kc * 32 + fo);
            d0a = __builtin_amdgcn_mfma_f32_16x16x32_f16(af, Bf0[kc], d0a, 0, 0, 0);
            d1a = __builtin_amdgcn_mfma_f32_16x16x32_f16(af, Bf1[kc], d1a, 0, 0, 0);
        }
        #pragma unroll
        for (int kc = 4; kc < 8; ++kc) {
            half8 af = *(const half8*)(pb + kc * 32 + fo);
            d0b = __builtin_amdgcn_mfma_f32_16x16x32_f16(af, Bf0[kc], d0b, 0, 0, 0);
            d1b = __builtin_amdgcn_mfma_f32_16x16x32_f16(af, Bf1[kc], d1b, 0, 0, 0);
        }
        float sva = d0a.x + d0b.x;              // Smv[32w + (lane&15)]
        float svb = d1a.x + d1b.x;              // Smv[32w + 16 + (lane&15)]
        float mySmv = (lane & 16) ? svb : sva;  // own column

        float m_next = 0.0f;
        if (even) {
            // anchor feed: wave max via DPP row_ror
            float mx = fmaxf(sva, svb);
            mx = dpp_maxf<0x121>(mx);   // ror:1
            mx = dpp_maxf<0x122>(mx);   // ror:2
            mx = dpp_maxf<0x124>(mx);   // ror:4
            mx = dpp_maxf<0x128>(mx);   // ror:8
            if (lane == 0) lds_red[w] = m_anchor + flog2(fmaxf(mx, 1e-30f));
        } else {
            float m1 = fmaxf(fmaxf(r0.x, r0.y), fmaxf(r0.z, r0.w));
            float m2 = fmaxf(fmaxf(r1.x, r1.y), fmaxf(r1.z, r1.w));
            m_next = fmaxf(m1, m2);
        }

        // ---- insert + PAIR shift/rescale: 15 v_pk_mul_f32 + 2 fixups ----
        float nv0 = mySmv * ga * ga;            // exp2(vnew - mcol)
        float rsc = frcp(fmaxf(nv0, 1.0f));     // exp2(mcol - mnew)
        float nv  = fminf(nv0, 1.0f);           // exp2(vnew - mnew)
        mcol = fmaxf(mcol, mac + flog2(mySmv)); // exact-log anchor update

        f32x2 hp  = xchg32(v[15].y);            // q0 age-32 <-> q1 age-64
        float oth = (hp.x == v[15].y) ? hp.y : hp.x;
        float p15lo = v[15].x;                  // own age 32q+16 (pre-shift)
        f32x2 rp = { rsc, rsc };
        #pragma unroll
        for (int k = 15; k >= 1; --k)
            v[k] = pk_mul(v[k - 1], rp);        // ages +1, both halves
        v[0].y = p15lo * rsc;                   // age 32q+17 <- old 32q+16
        v[0].x = (q == 0) ? nv : oth * rsc;     // age 1 <- insert ; 33 <- old 32

        if (!even && t + 1 < T_) m_anchor = m_next;  // keep final anchor for loglik
    };

    for (int t = 0; t < T_; t += 2) {
        body(t,     0, true );
        body(t + 1, 1, false);
    }

    // ---- loglik: lds_ph[1] holds f16 exp2(alpha_{T-1} - m_anchor) ----
    if (tid < 64) {
        const _Float16* lp = lds_ph[(T_ - 1) & 1];
        float sf = (float)lp[tid] + (float)lp[tid + 64]
                 + (float)lp[tid + 128] + (float)lp[tid + 192];
        #pragma unroll
        for (int off = 1; off < 64; off <<= 1)
            sf += __shfl_xor(sf, off, 64);
        if (tid == 0) out[b] = (m_anchor + flog2(sf)) * LN2;
    }
}

extern "C" void kernel_launch(void* const* d_in, const int* in_sizes, int n_in,
                              void* d_out, int out_size, void* d_ws, size_t ws_size,
                              hipStream_t stream) {
    const float* logB = (const float*)d_in[0];   // [16,2048,256]
    const float* pi   = (const float*)d_in[1];   // [256]
    const float* A    = (const float*)d_in[2];   // [256,256]
    const float* D    = (const float*)d_in[3];   // [256,64]
    float* out = (float*)d_out;
    (void)in_sizes; (void)n_in; (void)d_ws; (void)ws_size; (void)out_size;

    hipLaunchKernelGGL(hsmm_fwd_kernel, dim3(B_), dim3(512), 0, stream,
                       logB, pi, A, D, out);
}

// Round 11
// 1439.593 us; speedup vs baseline: 1.4656x; 1.0207x over previous
//
#include <hip/hip_runtime.h>
#include <cstddef>

#define LOG2E 1.4426950408889634f
#define LN2   0.6931471805599453f

typedef float    f32x2 __attribute__((ext_vector_type(2)));
typedef float    f32x4 __attribute__((ext_vector_type(4)));
typedef _Float16 half8 __attribute__((ext_vector_type(8)));

constexpr int K_    = 256;
constexpr int T_    = 2048;
constexpr int DMAX_ = 64;
constexpr int B_    = 16;

__device__ __forceinline__ float fexp2(float x) { return __builtin_amdgcn_exp2f(x); }
__device__ __forceinline__ float flog2(float x) { return __builtin_amdgcn_logf(x); }
__device__ __forceinline__ float frcp (float x) { return __builtin_amdgcn_rcpf(x); }

// cross-half (lane ^ 32) exchange via v_permlane32_swap_b32.
// %1 is "=&v" (early-clobber): guaranteed distinct from %2 and %0; %0 may share
// with %2 which is still correct (mov copies before swap). r.x+r.y is the
// cross-half sum either way; "other half's value" = whichever differs from own.
__device__ __forceinline__ f32x2 xchg32(float x) {
    float a = x, b;
    asm("v_mov_b32 %1, %2\n\t"
        "s_nop 1\n\t"
        "v_permlane32_swap_b32 %0, %1"
        : "+v"(a), "=&v"(b)
        : "v"(x));
    return (f32x2){a, b};
}

// max-reduce across a 16-lane row via DPP row_ror (VALU, no LDS pipe).
template<int CTRL>
__device__ __forceinline__ float dpp_maxf(float x) {
    int m = __builtin_amdgcn_update_dpp(0, __builtin_bit_cast(int, x), CTRL, 0xF, 0xF, true);
    return fmaxf(x, __builtin_bit_cast(float, m));
}

// BEST-MEASURED configuration (R4, 1385 us): 512 threads = 8 waves, 2
// waves/SIMD. Wave w owns columns 32w..32w+31.
// Lane map: j = (w<<5)|(lane&31); q = lane>>5 owns ages 32q+1..32q+32.
// PAIR-FRIENDLY AGE LAYOUT: v[i] holds ages {32q+1+i, 32q+17+i}, so the age
// shift maps whole pairs: v[i] <- v[i-1]*rsc = v_pk_mul_f32 x15 and the dot
// is 16 v_pk_fma_f32. Anchor machinery at HALF rate via static even/odd
// bodies (even: DPP max + lds_red write; odd: read + reduce).
// One pinned barrier per step; depth-3 global prefetch ring.
// This point is the measured joint optimum of {waves, LDS-ops, chain}:
// R5 (16 waves) +25%, R7 (4 waves) +36%, R3 (pipelined) +17%, R8 (batch-
// packed) +52%, R10 (forced VOP3P) neutral.
__global__ __launch_bounds__(512)
__attribute__((amdgpu_waves_per_eu(2, 2)))
void hsmm_fwd_kernel(const float* __restrict__ logB,   // [B,T,K]
                     const float* __restrict__ pi,     // [K]
                     const float* __restrict__ A,      // [K,K]
                     const float* __restrict__ D,      // [K,DMAX]
                     float* __restrict__ out)          // [16] loglik ++ [B,T,K] alphas
{
    const int b    = blockIdx.x;
    const int tid  = threadIdx.x;
    const int w    = tid >> 6;
    const int lane = tid & 63;
    const int j    = (w << 5) | (lane & 31);   // column 0..255
    const int q    = lane >> 5;                // age half

    alignas(16) __shared__ _Float16 lds_ph[2][K_];    // p f16, ping-pong by t&1
    alignas(16) __shared__ float    lds_red[8];       // per-wave max a_in

    // ---- init: B-fragments (P = exp(A_logits), f16, MFMA B-layout) ----
    half8 Bf0[8], Bf1[8];
    {
        const int krow = (lane >> 4) * 8;
        const int n0   = (w << 5) + (lane & 15);
        #pragma unroll
        for (int kc = 0; kc < 8; ++kc) {
            #pragma unroll
            for (int jj = 0; jj < 8; ++jj) {
                const int k = kc * 32 + krow + jj;
                Bf0[kc][jj] = (_Float16)fexp2(A[(size_t)k * K_ + n0     ] * LOG2E);
                Bf1[kc][jj] = (_Float16)fexp2(A[(size_t)k * K_ + n0 + 16] * LOG2E);
            }
        }
    }
    // pD in PAIR layout: pDf[i] = {pD(age 32q+1+i), pD(age 32q+17+i)}
    f32x2 pDf[16];
    {
        const float* Dj = D + (size_t)j * DMAX_ + 32 * q;
        #pragma unroll
        for (int i = 0; i < 16; ++i)
            pDf[i] = (f32x2){ fexp2(Dj[i] * LOG2E), fexp2(Dj[16 + i] * LOG2E) };
    }

    // v[i] = values at ages {32q+1+i, 32q+17+i}
    f32x2 v[16];
    #pragma unroll
    for (int i = 0; i < 16; ++i) v[i] = (f32x2){0.0f, 0.0f};
    if (q == 0) v[0].x = 1.0f;          // age-1 holds pi mass (anchor = pi)
    float mcol     = pi[j] * LOG2E;     // column anchor (base-2)
    float cumb     = 0.0f;
    float m_anchor = 0.0f;              // block anchor (lag 2-3)

    if (tid < 8) lds_red[tid] = 0.0f;
    __syncthreads();

    const float* lb = logB + (size_t)b * T_ * K_ + j;
    float*       ao = out + 16 + (size_t)b * T_ * K_ + j;

    // depth-3 prefetch ring for the per-step emission
    float bld0 = lb[0];
    float bld1 = lb[K_];
    float bld2 = lb[2 * K_];
    int   ldoff = 3 * K_;
    int   aoff  = 0;

    // static even/odd step body (EVEN: anchor-feed write; ODD: anchor update)
    auto body = [&](int t, int s, bool even) __attribute__((always_inline)) {
        cumb = fmaf(bld0, LOG2E, cumb);

        const float argh = 0.5f * (cumb + mcol - m_anchor);
        const float ea   = fminf(fexp2(argh),  1.8e19f);
        const float ga   = fminf(fexp2(-argh), 1.8e19f);
        const float mac  = m_anchor - cumb;

        // ---- duration dot: 16 pk_fma + tree + 1 permlane ----
        f32x2 s0 = {0.f,0.f}, s1 = {0.f,0.f}, s2 = {0.f,0.f}, s3 = {0.f,0.f};
        #pragma unroll
        for (int k = 0; k < 16; k += 4) {
            s0 = __builtin_elementwise_fma(v[k + 0], pDf[k + 0], s0);
            s1 = __builtin_elementwise_fma(v[k + 1], pDf[k + 1], s1);
            s2 = __builtin_elementwise_fma(v[k + 2], pDf[k + 2], s2);
            s3 = __builtin_elementwise_fma(v[k + 3], pDf[k + 3], s3);
        }
        f32x2 sp = (s0 + s1) + (s2 + s3);
        float Sl = sp.x + sp.y;
        f32x2 pr = xchg32(Sl);
        float S  = pr.x + pr.y;                 // full sum, direction-agnostic

        float p = fminf(S * ea * ea, 60000.0f); // f16-overflow clamp
        if (q == 0) lds_ph[s][j] = (_Float16)p;

        // ---- the ONE barrier: pinned so no LDS op crosses it ----
        asm volatile("s_waitcnt lgkmcnt(0)" ::: "memory");
        __builtin_amdgcn_sched_barrier(0);
        __builtin_amdgcn_s_barrier();
        __builtin_amdgcn_sched_barrier(0);

        // globals: prefetch t+3 (in flight across barriers) + alpha store
        bld0 = bld1; bld1 = bld2;
        bld2 = lb[ldoff];
        ldoff += (ldoff < (T_ - 1) * K_) ? K_ : 0;
        if (q == 0) ao[aoff] = (cumb + mcol + flog2(S)) * LN2;
        aoff += K_;

        f32x4 r0, r1;
        if (!even) {    // hoisted anchor read (latency overlaps MFMA)
            r0 = ((const f32x4*)lds_red)[0];
            r1 = ((const f32x4*)lds_red)[1];
        }

        // ---- MFMA matvec, 4 independent 4-deep chains ----
        const _Float16* pb = lds_ph[s];
        const int fo = (lane >> 4) * 8;
        const f32x4 z = {0.f,0.f,0.f,0.f};
        f32x4 d0a = z, d0b = z, d1a = z, d1b = z;
        #pragma unroll
        for (int kc = 0; kc < 4; ++kc) {
            half8 af = *(const half8*)(pb + kc * 32 + fo);
            d0a = __builtin_amdgcn_mfma_f32_16x16x32_f16(af, Bf0[kc], d0a, 0, 0, 0);
            d1a = __builtin_amdgcn_mfma_f32_16x16x32_f16(af, Bf1[kc], d1a, 0, 0, 0);
        }
        #pragma unroll
        for (int kc = 4; kc < 8; ++kc) {
            half8 af = *(const half8*)(pb + kc * 32 + fo);
            d0b = __builtin_amdgcn_mfma_f32_16x16x32_f16(af, Bf0[kc], d0b, 0, 0, 0);
            d1b = __builtin_amdgcn_mfma_f32_16x16x32_f16(af, Bf1[kc], d1b, 0, 0, 0);
        }
        float sva = d0a.x + d0b.x;              // Smv[32w + (lane&15)]
        float svb = d1a.x + d1b.x;              // Smv[32w + 16 + (lane&15)]
        float mySmv = (lane & 16) ? svb : sva;  // own column

        float m_next = 0.0f;
        if (even) {
            // anchor feed: wave max via DPP row_ror, write lds_red (read next step)
            float mx = fmaxf(sva, svb);
            mx = dpp_maxf<0x121>(mx);   // ror:1
            mx = dpp_maxf<0x122>(mx);   // ror:2
            mx = dpp_maxf<0x124>(mx);   // ror:4
            mx = dpp_maxf<0x128>(mx);   // ror:8
            if (lane == 0) lds_red[w] = m_anchor + flog2(fmaxf(mx, 1e-30f));
        } else {
            float m1 = fmaxf(fmaxf(r0.x, r0.y), fmaxf(r0.z, r0.w));
            float m2 = fmaxf(fmaxf(r1.x, r1.y), fmaxf(r1.z, r1.w));
            m_next = fmaxf(m1, m2);
        }

        // ---- insert + PAIR shift/rescale: 15 pk_mul + 2 fixups ----
        float nv0 = mySmv * ga * ga;            // exp2(vnew - mcol)
        float rsc = frcp(fmaxf(nv0, 1.0f));     // exp2(mcol - mnew)
        float nv  = fminf(nv0, 1.0f);           // exp2(vnew - mnew)
        mcol = fmaxf(mcol, mac + flog2(mySmv)); // exact-log anchor update

        f32x2 hp  = xchg32(v[15].y);            // q0 age-32 <-> q1 age-64
        float oth = (hp.x == v[15].y) ? hp.y : hp.x;
        float p15lo = v[15].x;                  // own age 32q+16 (pre-shift)
        f32x2 rp = { rsc, rsc };
        #pragma unroll
        for (int k = 15; k >= 1; --k)
            v[k] = v[k - 1] * rp;               // ages {k+.., k+16+..} <- {k-1.., k+15..}
        v[0].y = p15lo * rsc;                   // age 32q+17 <- old 32q+16
        v[0].x = (q == 0) ? nv : oth * rsc;     // age 1 <- insert ; age 33 <- old 32

        if (!even && t + 1 < T_) m_anchor = m_next;  // keep final anchor for loglik
    };

    for (int t = 0; t < T_; t += 2) {
        body(t,     0, true );
        body(t + 1, 1, false);
    }

    // ---- loglik: lds_ph[1] holds f16 exp2(alpha_{T-1} - m_anchor) ----
    if (tid < 64) {
        const _Float16* lp = lds_ph[(T_ - 1) & 1];
        float sf = (float)lp[tid] + (float)lp[tid + 64]
                 + (float)lp[tid + 128] + (float)lp[tid + 192];
        #pragma unroll
        for (int off = 1; off < 64; off <<= 1)
            sf += __shfl_xor(sf, off, 64);
        if (tid == 0) out[b] = (m_anchor + flog2(sf)) * LN2;
    }
}

extern "C" void kernel_launch(void* const* d_in, const int* in_sizes, int n_in,
                              void* d_out, int out_size, void* d_ws, size_t ws_size,
                              hipStream_t stream) {
    const float* logB = (const float*)d_in[0];   // [16,2048,256]
    const float* pi   = (const float*)d_in[1];   // [256]
    const float* A    = (const float*)d_in[2];   // [256,256]
    const float* D    = (const float*)d_in[3];   // [256,64]
    float* out = (float*)d_out;
    (void)in_sizes; (void)n_in; (void)d_ws; (void)ws_size; (void)out_size;

    hipLaunchKernelGGL(hsmm_fwd_kernel, dim3(B_), dim3(512), 0, stream,
                       logB, pi, A, D, out);
}

// Round 12
// 1424.785 us; speedup vs baseline: 1.4808x; 1.0104x over previous
//
#include <hip/hip_runtime.h>
#include <cstddef>

#define LOG2E 1.4426950408889634f
#define LN2   0.6931471805599453f

typedef float    f32x2 __attribute__((ext_vector_type(2)));
typedef float    f32x4 __attribute__((ext_vector_type(4)));
typedef _Float16 half8 __attribute__((ext_vector_type(8)));

constexpr int K_    = 256;
constexpr int T_    = 2048;
constexpr int DMAX_ = 64;
constexpr int B_    = 16;

__device__ __forceinline__ float fexp2(float x) { return __builtin_amdgcn_exp2f(x); }
__device__ __forceinline__ float flog2(float x) { return __builtin_amdgcn_logf(x); }
__device__ __forceinline__ float frcp (float x) { return __builtin_amdgcn_rcpf(x); }

// cross-half (lane ^ 32) exchange via v_permlane32_swap_b32.
// %1 early-clobber guarantees distinct regs; r.x+r.y = cross-half sum under
// either HW swap convention; which element is "own" is resolved once at init.
__device__ __forceinline__ f32x2 xchg32(float x) {
    float a = x, b;
    asm("v_mov_b32 %1, %2\n\t"
        "s_nop 1\n\t"
        "v_permlane32_swap_b32 %0, %1"
        : "+v"(a), "=&v"(b)
        : "v"(x));
    return (f32x2){a, b};
}

// max-reduce across a 16-lane row via DPP row_ror (VALU, no LDS pipe).
template<int CTRL>
__device__ __forceinline__ float dpp_maxf(float x) {
    int m = __builtin_amdgcn_update_dpp(0, __builtin_bit_cast(int, x), CTRL, 0xF, 0xF, true);
    return fmaxf(x, __builtin_bit_cast(float, m));
}

// R4 structure (best-measured 1378-1386 us) + post-barrier critical-window
// code motion (this round):
//   (1) af ds_read_b128 x8 issued FIRST after the barrier; global prefetch/
//       alpha-store/anchor-read moved into their latency shadow.
//   (2) age-handoff xchg32(v[15].y) hoisted into phase A (input stable since
//       the previous shift) -- off the tail chain.
//   (3) permlane swap direction resolved ONCE at init (probe exchange).
// 512 threads = 8 waves, 2 waves/SIMD. Wave w owns columns 32w..32w+31.
// Lane map: j = (w<<5)|(lane&31); q = lane>>5 owns ages 32q+1..32q+32 as
// pairs v[i] = {32q+1+i, 32q+17+i} (pair-shift layout). Anchor machinery at
// half rate (even: DPP max + lds_red write; odd: read + reduce). One pinned
// barrier per step; depth-3 global prefetch ring.
__global__ __launch_bounds__(512)
__attribute__((amdgpu_waves_per_eu(2, 2)))
void hsmm_fwd_kernel(const float* __restrict__ logB,   // [B,T,K]
                     const float* __restrict__ pi,     // [K]
                     const float* __restrict__ A,      // [K,K]
                     const float* __restrict__ D,      // [K,DMAX]
                     float* __restrict__ out)          // [16] loglik ++ [B,T,K] alphas
{
    const int b    = blockIdx.x;
    const int tid  = threadIdx.x;
    const int w    = tid >> 6;
    const int lane = tid & 63;
    const int j    = (w << 5) | (lane & 31);   // column 0..255
    const int q    = lane >> 5;                // age half

    alignas(16) __shared__ _Float16 lds_ph[2][K_];    // p f16, ping-pong by t&1
    alignas(16) __shared__ float    lds_red[8];       // per-wave max a_in

    // ---- init: B-fragments (P = exp(A_logits), f16, MFMA B-layout) ----
    half8 Bf0[8], Bf1[8];
    {
        const int krow = (lane >> 4) * 8;
        const int n0   = (w << 5) + (lane & 15);
        #pragma unroll
        for (int kc = 0; kc < 8; ++kc) {
            #pragma unroll
            for (int jj = 0; jj < 8; ++jj) {
                const int k = kc * 32 + krow + jj;
                Bf0[kc][jj] = (_Float16)fexp2(A[(size_t)k * K_ + n0     ] * LOG2E);
                Bf1[kc][jj] = (_Float16)fexp2(A[(size_t)k * K_ + n0 + 16] * LOG2E);
            }
        }
    }
    // pD in PAIR layout: pDf[i] = {pD(age 32q+1+i), pD(age 32q+17+i)}
    f32x2 pDf[16];
    {
        const float* Dj = D + (size_t)j * DMAX_ + 32 * q;
        #pragma unroll
        for (int i = 0; i < 16; ++i)
            pDf[i] = (f32x2){ fexp2(Dj[i] * LOG2E), fexp2(Dj[16 + i] * LOG2E) };
    }

    // resolve permlane32_swap convention once: which element is OWN value
    bool x_is_own;
    {
        f32x2 tp = xchg32((float)(q + 1));
        x_is_own = (tp.x == (float)(q + 1));
    }

    // v[i] = values at ages {32q+1+i, 32q+17+i}
    f32x2 v[16];
    #pragma unroll
    for (int i = 0; i < 16; ++i) v[i] = (f32x2){0.0f, 0.0f};
    if (q == 0) v[0].x = 1.0f;          // age-1 holds pi mass (anchor = pi)
    float mcol     = pi[j] * LOG2E;     // column anchor (base-2)
    float cumb     = 0.0f;
    float m_anchor = 0.0f;              // block anchor (lag 2-3)

    if (tid < 8) lds_red[tid] = 0.0f;
    __syncthreads();

    const float* lb = logB + (size_t)b * T_ * K_ + j;
    float*       ao = out + 16 + (size_t)b * T_ * K_ + j;

    // depth-3 prefetch ring for the per-step emission
    float bld0 = lb[0];
    float bld1 = lb[K_];
    float bld2 = lb[2 * K_];
    int   ldoff = 3 * K_;
    int   aoff  = 0;

    // static even/odd step body (EVEN: anchor-feed write; ODD: anchor update)
    auto body = [&](int t, int s, bool even) __attribute__((always_inline)) {
        cumb = fmaf(bld0, LOG2E, cumb);

        const float argh = 0.5f * (cumb + mcol - m_anchor);
        const float ea   = fminf(fexp2(argh),  1.8e19f);
        const float ga   = fminf(fexp2(-argh), 1.8e19f);
        const float mac  = m_anchor - cumb;

        // ---- duration dot: 16 pk_fma + tree + 1 permlane ----
        f32x2 s0 = {0.f,0.f}, s1 = {0.f,0.f}, s2 = {0.f,0.f}, s3 = {0.f,0.f};
        #pragma unroll
        for (int k = 0; k < 16; k += 4) {
            s0 = __builtin_elementwise_fma(v[k + 0], pDf[k + 0], s0);
            s1 = __builtin_elementwise_fma(v[k + 1], pDf[k + 1], s1);
            s2 = __builtin_elementwise_fma(v[k + 2], pDf[k + 2], s2);
            s3 = __builtin_elementwise_fma(v[k + 3], pDf[k + 3], s3);
        }
        f32x2 sp = (s0 + s1) + (s2 + s3);
        float Sl = sp.x + sp.y;
        f32x2 pr = xchg32(Sl);
        float S  = pr.x + pr.y;                 // full sum, direction-agnostic

        // age-handoff exchange HOISTED off the tail chain (v stable until shift)
        f32x2 hp    = xchg32(v[15].y);          // q0 age-32 <-> q1 age-64
        float oth   = x_is_own ? hp.y : hp.x;   // the other half's value
        float p15lo = v[15].x;                  // own age 32q+16 (pre-shift)

        float p = fminf(S * ea * ea, 60000.0f); // f16-overflow clamp
        if (q == 0) lds_ph[s][j] = (_Float16)p;

        // ---- the ONE barrier: pinned so no LDS op crosses it ----
        asm volatile("s_waitcnt lgkmcnt(0)" ::: "memory");
        __builtin_amdgcn_sched_barrier(0);
        __builtin_amdgcn_s_barrier();
        __builtin_amdgcn_sched_barrier(0);

        // ---- af fragment reads FIRST (head of the post-barrier chain) ----
        const _Float16* pb = lds_ph[s];
        const int fo = (lane >> 4) * 8;
        half8 af[8];
        #pragma unroll
        for (int kc = 0; kc < 8; ++kc)
            af[kc] = *(const half8*)(pb + kc * 32 + fo);

        // globals issue in the ds_read latency shadow:
        // prefetch t+3 (in flight across barriers) + alpha store
        bld0 = bld1; bld1 = bld2;
        bld2 = lb[ldoff];
        ldoff += (ldoff < (T_ - 1) * K_) ? K_ : 0;
        if (q == 0) ao[aoff] = (cumb + mcol + flog2(S)) * LN2;
        aoff += K_;

        f32x4 r0, r1;
        if (!even) {    // anchor read (latency overlaps MFMA)
            r0 = ((const f32x4*)lds_red)[0];
            r1 = ((const f32x4*)lds_red)[1];
        }

        // ---- MFMA matvec, 4 independent 4-deep chains ----
        const f32x4 z = {0.f,0.f,0.f,0.f};
        f32x4 d0a = z, d0b = z, d1a = z, d1b = z;
        #pragma unroll
        for (int kc = 0; kc < 4; ++kc) {
            d0a = __builtin_amdgcn_mfma_f32_16x16x32_f16(af[kc], Bf0[kc], d0a, 0, 0, 0);
            d1a = __builtin_amdgcn_mfma_f32_16x16x32_f16(af[kc], Bf1[kc], d1a, 0, 0, 0);
        }
        #pragma unroll
        for (int kc = 4; kc < 8; ++kc) {
            d0b = __builtin_amdgcn_mfma_f32_16x16x32_f16(af[kc], Bf0[kc], d0b, 0, 0, 0);
            d1b = __builtin_amdgcn_mfma_f32_16x16x32_f16(af[kc], Bf1[kc], d1b, 0, 0, 0);
        }
        float sva = d0a.x + d0b.x;              // Smv[32w + (lane&15)]
        float svb = d1a.x + d1b.x;              // Smv[32w + 16 + (lane&15)]
        float mySmv = (lane & 16) ? svb : sva;  // own column

        float m_next = 0.0f;
        if (even) {
            // anchor feed: wave max via DPP row_ror, write lds_red (read next step)
            float mx = fmaxf(sva, svb);
            mx = dpp_maxf<0x121>(mx);   // ror:1
            mx = dpp_maxf<0x122>(mx);   // ror:2
            mx = dpp_maxf<0x124>(mx);   // ror:4
            mx = dpp_maxf<0x128>(mx);   // ror:8
            if (lane == 0) lds_red[w] = m_anchor + flog2(fmaxf(mx, 1e-30f));
        } else {
            float m1 = fmaxf(fmaxf(r0.x, r0.y), fmaxf(r0.z, r0.w));
            float m2 = fmaxf(fmaxf(r1.x, r1.y), fmaxf(r1.z, r1.w));
            m_next = fmaxf(m1, m2);
        }

        // ---- insert + PAIR shift/rescale: 15 pk_mul + 2 fixups ----
        float nv0 = mySmv * ga * ga;            // exp2(vnew - mcol)
        float rsc = frcp(fmaxf(nv0, 1.0f));     // exp2(mcol - mnew)
        float nv  = fminf(nv0, 1.0f);           // exp2(vnew - mnew)
        mcol = fmaxf(mcol, mac + flog2(mySmv)); // exact-log anchor update

        f32x2 rp = { rsc, rsc };
        #pragma unroll
        for (int k = 15; k >= 1; --k)
            v[k] = v[k - 1] * rp;               // ages {k+.., k+16+..} <- {k-1.., k+15..}
        v[0].y = p15lo * rsc;                   // age 32q+17 <- old 32q+16
        v[0].x = (q == 0) ? nv : oth * rsc;     // age 1 <- insert ; age 33 <- old 32

        if (!even && t + 1 < T_) m_anchor = m_next;  // keep final anchor for loglik
    };

    for (int t = 0; t < T_; t += 2) {
        body(t,     0, true );
        body(t + 1, 1, false);
    }

    // ---- loglik: lds_ph[1] holds f16 exp2(alpha_{T-1} - m_anchor) ----
    if (tid < 64) {
        const _Float16* lp = lds_ph[(T_ - 1) & 1];
        float sf = (float)lp[tid] + (float)lp[tid + 64]
                 + (float)lp[tid + 128] + (float)lp[tid + 192];
        #pragma unroll
        for (int off = 1; off < 64; off <<= 1)
            sf += __shfl_xor(sf, off, 64);
        if (tid == 0) out[b] = (m_anchor + flog2(sf)) * LN2;
    }
}

extern "C" void kernel_launch(void* const* d_in, const int* in_sizes, int n_in,
                              void* d_out, int out_size, void* d_ws, size_t ws_size,
                              hipStream_t stream) {
    const float* logB = (const float*)d_in[0];   // [16,2048,256]
    const float* pi   = (const float*)d_in[1];   // [256]
    const float* A    = (const float*)d_in[2];   // [256,256]
    const float* D    = (const float*)d_in[3];   // [256,64]
    float* out = (float*)d_out;
    (void)in_sizes; (void)n_in; (void)d_ws; (void)ws_size; (void)out_size;

    hipLaunchKernelGGL(hsmm_fwd_kernel, dim3(B_), dim3(512), 0, stream,
                       logB, pi, A, D, out);
}